// Round 3
// baseline (327.331 us; speedup 1.0000x reference)
//
#include <hip/hip_runtime.h>
#include <stdint.h>

#define BB 8
#define LL 2048
#define DT 32
#define HID 544
#define REGP 5.0f
#define BETA0 0.4f
#define BETA1 0.3f
#define EPSV 1e-6f

typedef float v4 __attribute__((ext_vector_type(4)));

// Kernel A: 8 rows per block. hidden_vector (544 f32) + pre-exponentiated
// per-row scalars: paE=exp(pa_j), pbE=exp(pb_i+bl), gaE=exp(-5*ga_j),
// gbE=exp(-5*(gb_i+bg)).
__global__ __launch_bounds__(256) void prep_k(
    const int* __restrict__ etype, const float* __restrict__ etime,
    const float* __restrict__ wtpos, const float* __restrict__ temb,
    const float* __restrict__ wl, const float* __restrict__ wg,
    const float* __restrict__ blp, const float* __restrict__ bgp,
    float* __restrict__ hidden,
    float* __restrict__ paE, float* __restrict__ pbE,
    float* __restrict__ gaE, float* __restrict__ gbE)
{
    const int r0 = blockIdx.x << 3;      // first row (b*L+i) of this block
    const int tid = threadIdx.x;
    const float c = -0.03597789207803197f;   // -ln(10000)/256
    const float divt = __expf((float)tid * c);
    const float wt = wtpos[tid];
    const float bl = blp[0];
    const float bg = bgp[0];

    #pragma unroll
    for (int rr = 0; rr < 8; ++rr) {
        const int row = r0 + rr;
        const int i = row & (LL - 1);
        const float t = etime[row];
        float arc = fmaf((float)i, divt, t * wt);
        size_t hbase = (size_t)row * HID;
        __builtin_nontemporal_store(sinf(arc), hidden + hbase + tid);
        __builtin_nontemporal_store(cosf(arc), hidden + hbase + 256 + tid);

        if (tid < 32) {
            int ty = etype[row];
            float te = temb[ty * DT + tid];
            __builtin_nontemporal_store(te, hidden + hbase + 512 + tid);
            float va = te * wl[tid];
            float vb = te * wl[32 + tid];
            float vc = te * wg[tid];
            float vd = te * wg[32 + tid];
            #pragma unroll
            for (int m = 16; m > 0; m >>= 1) {
                va += __shfl_xor(va, m, 64);
                vb += __shfl_xor(vb, m, 64);
                vc += __shfl_xor(vc, m, 64);
                vd += __shfl_xor(vd, m, 64);
            }
            if (tid == 0) {
                paE[row] = __expf(va);
                pbE[row] = __expf(vb + bl);
                gaE[row] = __expf(-REGP * vc);
                gbE[row] = __expf(-REGP * (vd + bg));
            }
        }
    }
}

// Kernel B: scores + t_diff (f32, non-temporal). Grid (j-half, i-tile16, b);
// 256 threads, 4 consecutive j per thread, 16 i rows reusing j-side regs.
__global__ __launch_bounds__(256) void pair_k(
    const float* __restrict__ etime,
    const float* __restrict__ paE, const float* __restrict__ pbE,
    const float* __restrict__ gaE, const float* __restrict__ gbE,
    float* __restrict__ scores, float* __restrict__ tdiff)
{
    const int b  = blockIdx.z;
    const int i0 = blockIdx.y << 4;
    const int j0 = (blockIdx.x << 10) + (threadIdx.x << 2);
    const int rowb = b * LL;

    const v4 tj = *(const v4*)(etime + rowb + j0);
    const v4 pj = *(const v4*)(paE + rowb + j0);
    const v4 gj = *(const v4*)(gaE + rowb + j0);

    #pragma unroll 4
    for (int ii = 0; ii < 16; ++ii) {
        const int i = i0 + ii;
        const float ti  = etime[rowb + i];
        const float pbi = pbE[rowb + i];
        const float gbi = gbE[rowb + i];
        const size_t base = ((size_t)(rowb + i) << 11) + j0;

        v4 dd;
        dd.x = fabsf(tj.x - ti);
        dd.y = fabsf(tj.y - ti);
        dd.z = fabsf(tj.z - ti);
        dd.w = fabsf(tj.w - ti);
        __builtin_nontemporal_store(dd, (v4*)(tdiff + base));

        v4 sc;
        if (j0 < i) {
            float pjv[4] = {pj.x, pj.y, pj.z, pj.w};
            float gjv[4] = {gj.x, gj.y, gj.z, gj.w};
            float dv[4]  = {dd.x, dd.y, dd.z, dd.w};
            float s[4];
            #pragma unroll
            for (int e = 0; e < 4; ++e) {
                float l  = __logf(fmaf(pjv[e], pbi, 1.0f)) + EPSV;  // softplus
                float rl = __builtin_amdgcn_rcpf(l);
                float u  = dv[e] * rl;
                float kse = __expf(-0.5f * u * u);
                float kex = __expf(-u);
                float g   = __builtin_amdgcn_rcpf(fmaf(gjv[e], gbi, 1.0f));
                float v   = g * fmaf(BETA0, kse, BETA1 * kex);
                s[e] = ((j0 + e) < i) ? v : 0.0f;
            }
            sc.x = s[0]; sc.y = s[1]; sc.z = s[2]; sc.w = s[3];
        } else {
            sc = (v4)(0.0f);
        }
        __builtin_nontemporal_store(sc, (v4*)(scores + base));
    }
}

extern "C" void kernel_launch(void* const* d_in, const int* in_sizes, int n_in,
                              void* d_out, int out_size, void* d_ws, size_t ws_size,
                              hipStream_t stream) {
    const int*   etype = (const int*)d_in[0];
    const float* etime = (const float*)d_in[1];
    // d_in[2] arrival_times: unused by the reference
    const float* wtpos = (const float*)d_in[3];
    const float* temb  = (const float*)d_in[4];
    const float* wl    = (const float*)d_in[5];
    const float* blp   = (const float*)d_in[6];
    const float* wg    = (const float*)d_in[7];
    const float* bgp   = (const float*)d_in[8];

    float* out    = (float*)d_out;
    float* scores = out;                                  // [8,2048,2048]
    float* hidden = out + (size_t)BB * LL * LL;           // [8,2048,544]
    float* tdiff  = hidden + (size_t)BB * LL * HID;       // [8,2048,2048]

    float* paE = (float*)d_ws;
    float* pbE = paE + BB * LL;
    float* gaE = pbE + BB * LL;
    float* gbE = gaE + BB * LL;

    prep_k<<<BB * LL / 8, 256, 0, stream>>>(etype, etime, wtpos, temb, wl, wg,
                                            blp, bgp, hidden, paE, pbE, gaE, gbE);
    pair_k<<<dim3(2, LL / 16, BB), 256, 0, stream>>>(etime, paE, pbE, gaE, gbE,
                                                     scores, tdiff);
}